// Round 3
// baseline (267.001 us; speedup 1.0000x reference)
//
#include <hip/hip_runtime.h>
#include <cmath>

#define T_LEN 480000
#define BATCH 64
#define CHUNK 128
#define WARM  320
#define NCH   ((T_LEN + CHUNK - 1) / CHUNK)   // 3750 chunks per row
#define BLKS  32                               // samples per pipeline block (8 x float4)

// One biquad DF1 step. Critical path is a single dependent FMA per sample:
//   g = fma(c2, y2, f)  (y2 is 2 samples old -> off critical path)
//   y = fma(c1, y1, g)
#define STEP(xi, yo) do {                                   \
    float f_  = fmaf(b0, (xi), fmaf(b1, x1, b2 * x2));      \
    float g_  = fmaf(c2, y2, f_);                           \
    float yy_ = fmaf(c1, y1, g_);                           \
    x2 = x1; x1 = (xi);                                     \
    y2 = y1; y1 = yy_;                                      \
    (yo) = yy_;                                             \
} while (0)

__global__ __launch_bounds__(256) void highpass_kernel(
    const float* __restrict__ in, float* __restrict__ out,
    const float b0, const float b1, const float b2,
    const float c1, const float c2)
{
    const int idx = blockIdx.x * blockDim.x + threadIdx.x;
    if (idx >= BATCH * NCH) return;
    const int r = idx / NCH;
    const int c = idx - r * NCH;

    const size_t rowoff = (size_t)r * T_LEN;
    const int begin = c * CHUNK;
    int end = begin + CHUNK; if (end > T_LEN) end = T_LEN;
    int start = begin - WARM; if (start < 0) start = 0;

    // CHUNK and WARM are multiples of 32, and clamping start to 0 keeps
    // (end-start) a multiple of BLKS=32; start is 128B-aligned.
    const float4* __restrict__ xv = (const float4*)(in  + rowoff + start);
    float4*       __restrict__ yv = (float4*)      (out + rowoff + start);

    const int nblk = (end - start) / BLKS;    // total 32-sample blocks
    const int wblk = (begin - start) / BLKS;  // warm-up blocks (outputs discarded)

    float x1 = 0.f, x2 = 0.f, y1 = 0.f, y2 = 0.f;

    float4 cur[8], nxt[8];
#pragma unroll
    for (int i = 0; i < 8; ++i) cur[i] = xv[i];

    for (int b = 0; b < nblk; ++b) {
        // prefetch next block while computing current
        if (b + 1 < nblk) {
#pragma unroll
            for (int i = 0; i < 8; ++i) nxt[i] = xv[(b + 1) * 8 + i];
        }

        float4 o[8];
#pragma unroll
        for (int i = 0; i < 8; ++i) {
            float4 v = cur[i];
            float4 q;
            STEP(v.x, q.x);
            STEP(v.y, q.y);
            STEP(v.z, q.z);
            STEP(v.w, q.w);
            o[i] = q;
        }

        if (b >= wblk) {
#pragma unroll
            for (int i = 0; i < 8; ++i) yv[b * 8 + i] = o[i];
        }

#pragma unroll
        for (int i = 0; i < 8; ++i) cur[i] = nxt[i];
    }
}

extern "C" void kernel_launch(void* const* d_in, const int* in_sizes, int n_in,
                              void* d_out, int out_size, void* d_ws, size_t ws_size,
                              hipStream_t stream) {
    const float* in  = (const float*)d_in[0];
    float*       out = (float*)d_out;

    // RBJ highpass biquad coefficients (double precision on host, match reference)
    const double Q     = 0.7071067811865476;
    const double w0    = 2.0 * M_PI * 100.0 / 16000.0;
    const double alpha = sin(w0) / (2.0 * Q);
    const double cosw  = cos(w0);
    const double b0d = (1.0 + cosw) / 2.0;
    const double b1d = -(1.0 + cosw);
    const double b2d = b0d;
    const double a0d = 1.0 + alpha;
    const double a1d = -2.0 * cosw;
    const double a2d = 1.0 - alpha;

    const float b0 = (float)(b0d / a0d);
    const float b1 = (float)(b1d / a0d);
    const float b2 = (float)(b2d / a0d);
    const float c1 = (float)(-(a1d / a0d));
    const float c2 = (float)(-(a2d / a0d));

    const int total  = BATCH * NCH;            // 240000 threads = 3750 waves = 14.6/CU
    const int tblock = 256;
    const int grid   = (total + tblock - 1) / tblock;

    hipLaunchKernelGGL(highpass_kernel, dim3(grid), dim3(tblock), 0, stream,
                       in, out, b0, b1, b2, c1, c2);
}

// Round 4
// 230.660 us; speedup vs baseline: 1.1576x; 1.1576x over previous
//
#include <hip/hip_runtime.h>
#include <cmath>

#define T_LEN 480000
#define BATCH 64
#define L     64                 // samples per thread (chunk)
#define WARMT 6                  // warm threads per block (outputs discarded)
#define OUTT  (256 - WARMT)      // 250 output chunks per block
#define SPB   (OUTT * L)         // 16000 output samples per block
#define BPR   (T_LEN / SPB)      // 30 blocks per row (exact)

// One biquad DF1 step; single dependent FMA on the y-critical path.
#define STEP(xi, yo) do {                                   \
    float f_  = fmaf(b0, (xi), fmaf(b1, x1, b2 * x2));      \
    float g_  = fmaf(c2, y2, f_);                           \
    float yy_ = fmaf(c1, y1, g_);                           \
    x2 = x1; x1 = (xi);                                     \
    y2 = y1; y1 = yy_;                                      \
    (yo) = yy_;                                             \
} while (0)

__global__ __launch_bounds__(256) void highpass_kernel(
    const float* __restrict__ in, float* __restrict__ out,
    const float b0, const float b1, const float b2,
    const float c1, const float c2,
    const float4 M1, const float4 M2, const float4 M3,
    const float4 M4, const float4 M5)
{
    const int r = blockIdx.x / BPR;
    const int b = blockIdx.x - r * BPR;
    const int t = threadIdx.x;
    const size_t rowoff = (size_t)r * T_LEN;
    const int start = b * SPB + (t - WARMT) * L;  // <0 only for warm threads of block 0

    float4 v[16];                 // the thread's 64 input samples, held in regs
    float pa = 0.f, pb = 0.f;     // provisional final (y_{L-1}, y_{L-2})
    float xs1 = 0.f, xs2 = 0.f;   // x-seed (exact, read directly)

    const bool active = (start >= 0);
    if (active) {
        const float4* __restrict__ xv = (const float4*)(in + rowoff + start);
#pragma unroll
        for (int i = 0; i < 16; ++i) v[i] = xv[i];
        if (start > 0) {
            xs1 = in[rowoff + start - 1];
            xs2 = in[rowoff + start - 2];
        }
        // Pass A: zero y-state provisional scan (outputs discarded)
        float x1 = xs1, x2 = xs2, y1 = 0.f, y2 = 0.f;
#pragma unroll
        for (int i = 0; i < 16; ++i) {
            float d;
            STEP(v[i].x, d); STEP(v[i].y, d); STEP(v[i].z, d); STEP(v[i].w, d);
        }
        pa = y1; pb = y2;
    }

    __shared__ float2 pl[256];
    pl[t] = make_float2(pa, pb);
    __syncthreads();
    if (t < WARMT) return;        // warm threads done

    // True incoming state: S_{t-1} = p_{t-1} + M p_{t-2} + ... + M^5 p_{t-6}
    // (M = A^64, ||M^6|| ~ 2e-5 -> truncation negligible)
    const float2 q1 = pl[t - 1], q2 = pl[t - 2], q3 = pl[t - 3],
                 q4 = pl[t - 4], q5 = pl[t - 5], q6 = pl[t - 6];
    float Y1 = q1.x, Y2 = q1.y;
    Y1 = fmaf(M1.x, q2.x, fmaf(M1.y, q2.y, Y1));
    Y2 = fmaf(M1.z, q2.x, fmaf(M1.w, q2.y, Y2));
    Y1 = fmaf(M2.x, q3.x, fmaf(M2.y, q3.y, Y1));
    Y2 = fmaf(M2.z, q3.x, fmaf(M2.w, q3.y, Y2));
    Y1 = fmaf(M3.x, q4.x, fmaf(M3.y, q4.y, Y1));
    Y2 = fmaf(M3.z, q4.x, fmaf(M3.w, q4.y, Y2));
    Y1 = fmaf(M4.x, q5.x, fmaf(M4.y, q5.y, Y1));
    Y2 = fmaf(M4.z, q5.x, fmaf(M4.w, q5.y, Y2));
    Y1 = fmaf(M5.x, q6.x, fmaf(M5.y, q6.y, Y1));
    Y2 = fmaf(M5.z, q6.x, fmaf(M5.w, q6.y, Y2));

    // Pass B: exact scan with true state, outputs overwrite v[] in regs
    {
        float x1 = xs1, x2 = xs2, y1 = Y1, y2 = Y2;
#pragma unroll
        for (int i = 0; i < 16; ++i) {
            float4 q;
            STEP(v[i].x, q.x); STEP(v[i].y, q.y);
            STEP(v[i].z, q.z); STEP(v[i].w, q.w);
            v[i] = q;
        }
    }

    float4* __restrict__ yv = (float4*)(out + rowoff + start);
#pragma unroll
    for (int i = 0; i < 16; ++i) yv[i] = v[i];
}

static void matmul2(const double* a, const double* bm, double* o) {
    o[0] = a[0]*bm[0] + a[1]*bm[2];
    o[1] = a[0]*bm[1] + a[1]*bm[3];
    o[2] = a[2]*bm[0] + a[3]*bm[2];
    o[3] = a[2]*bm[1] + a[3]*bm[3];
}

extern "C" void kernel_launch(void* const* d_in, const int* in_sizes, int n_in,
                              void* d_out, int out_size, void* d_ws, size_t ws_size,
                              hipStream_t stream) {
    const float* in  = (const float*)d_in[0];
    float*       out = (float*)d_out;

    // RBJ highpass biquad coefficients (double precision, matches reference)
    const double Q     = 0.7071067811865476;
    const double w0    = 2.0 * M_PI * 100.0 / 16000.0;
    const double alpha = sin(w0) / (2.0 * Q);
    const double cosw  = cos(w0);
    const double b0d = (1.0 + cosw) / 2.0;
    const double b1d = -(1.0 + cosw);
    const double b2d = b0d;
    const double a0d = 1.0 + alpha;
    const double c1d = -(-2.0 * cosw) / a0d;   // -a1/a0
    const double c2d = -(1.0 - alpha) / a0d;   // -a2/a0

    // M = A^L (A = [[c1,c2],[1,0]]) via repeated squaring, then powers M^1..M^5
    double A[4] = {c1d, c2d, 1.0, 0.0};
    double M[4] = {A[0], A[1], A[2], A[3]};
    for (int s = 0; s < 6; ++s) {           // A^2, A^4, ..., A^64  (L=64)
        double tmp[4]; matmul2(M, M, tmp);
        M[0]=tmp[0]; M[1]=tmp[1]; M[2]=tmp[2]; M[3]=tmp[3];
    }
    double P[5][4];
    P[0][0]=M[0]; P[0][1]=M[1]; P[0][2]=M[2]; P[0][3]=M[3];
    for (int k = 1; k < 5; ++k) matmul2(P[k-1], M, P[k]);

    float4 Mv[5];
    for (int k = 0; k < 5; ++k)
        Mv[k] = make_float4((float)P[k][0], (float)P[k][1],
                            (float)P[k][2], (float)P[k][3]);

    const float b0 = (float)(b0d / a0d);
    const float b1 = (float)(b1d / a0d);
    const float b2 = (float)(b2d / a0d);
    const float c1 = (float)c1d;
    const float c2 = (float)c2d;

    const int grid = BATCH * BPR;   // 1920 blocks x 256 threads = 7680 waves
    hipLaunchKernelGGL(highpass_kernel, dim3(grid), dim3(256), 0, stream,
                       in, out, b0, b1, b2, c1, c2,
                       Mv[0], Mv[1], Mv[2], Mv[3], Mv[4]);
}